// Round 2
// baseline (370.239 us; speedup 1.0000x reference)
//
#include <hip/hip_runtime.h>

// FocalLoss (RetinaNet-style), B=8, A=100000, C=80, M=64, all fp32.
// d_in: [0] classifications (B,A,C), [1] regressions (B,A,4),
//       [2] anchors (1,A,4), [3] annotations (B,M,5)
// d_out: 2 floats: [clf_mean, reg_mean]

constexpr int B_ = 8;
constexpr int A_ = 100000;
constexpr int C_ = 80;
constexpr int M_ = 64;
constexpr int APB = 256;  // anchors per block

struct Ws {
  double cls_sum[B_];
  double reg_sum[B_];
  unsigned num_pos[B_];
};

__global__ __launch_bounds__(APB) void focal_main(
    const float* __restrict__ cls, const float* __restrict__ reg,
    const float* __restrict__ anchors, const float* __restrict__ ann,
    Ws* __restrict__ ws) {
  __shared__ float s_ann[M_ * 5];
  __shared__ unsigned char s_state[APB];  // 0=ignore, 1=neg, 2=pos
  __shared__ unsigned char s_cidx[APB];
  __shared__ float s_c[4], s_r[4];
  __shared__ int s_p[4];

  const int b = blockIdx.y;
  const int a0 = blockIdx.x * APB;
  const int tid = threadIdx.x;

  // stage this image's annotations
  for (int i = tid; i < M_ * 5; i += APB) s_ann[i] = ann[b * M_ * 5 + i];
  __syncthreads();

  float reg_local = 0.0f;
  float cls_local = 0.0f;
  int pos_local = 0;
  int state = 0, cidx = 0;
  const int a = a0 + tid;

  if (a < A_) {
    const float4 ab = *(const float4*)(anchors + (size_t)a * 4);
    const float area_a = (ab.z - ab.x) * (ab.w - ab.y);
    float best = -1e30f;
    int bestm = 0;
#pragma unroll 8
    for (int m = 0; m < M_; ++m) {
      const float bx1 = s_ann[m * 5 + 0], by1 = s_ann[m * 5 + 1];
      const float bx2 = s_ann[m * 5 + 2], by2 = s_ann[m * 5 + 3];
      const float lab = s_ann[m * 5 + 4];
      float iw = fminf(ab.z, bx2) - fmaxf(ab.x, bx1);
      float ih = fminf(ab.w, by2) - fmaxf(ab.y, by1);
      iw = fmaxf(iw, 0.0f);
      ih = fmaxf(ih, 0.0f);
      const float inter = iw * ih;
      const float area_b = (bx2 - bx1) * (by2 - by1);
      const float ua = fmaxf(area_a + area_b - inter, 1e-8f);
      float iou = inter / ua;
      iou = (lab != -1.0f) ? iou : -1.0f;
      if (iou > best) { best = iou; bestm = m; }  // strict > == first-occurrence argmax
    }
    const bool pos = best > 0.1f;
    const bool neg = best <= 0.01f;
    state = pos ? 2 : (neg ? 1 : 0);
    if (pos) {
      pos_local = 1;
      const float gx1 = s_ann[bestm * 5 + 0], gy1 = s_ann[bestm * 5 + 1];
      const float gx2 = s_ann[bestm * 5 + 2], gy2 = s_ann[bestm * 5 + 3];
      cidx = (int)fmaxf(s_ann[bestm * 5 + 4], 0.0f);
      const float aw = ab.z - ab.x, ah = ab.w - ab.y;
      const float acx = ab.x + 0.5f * aw, acy = ab.y + 0.5f * ah;
      const float gw0 = gx2 - gx1, gh0 = gy2 - gy1;
      const float gcx = gx1 + 0.5f * gw0, gcy = gy1 + 0.5f * gh0;
      const float gw = fmaxf(gw0, 1.0f), gh = fmaxf(gh0, 1.0f);
      const float4 rg = *(const float4*)(reg + ((size_t)b * A_ + a) * 4);
      const float t0 = ((gcx - acx) / aw) / 0.1f;
      const float t1 = ((gcy - acy) / ah) / 0.1f;
      const float t2 = logf(gw / aw) / 0.2f;
      const float t3 = logf(gh / ah) / 0.2f;
      const float d0 = fabsf(t0 - rg.x);
      const float d1 = fabsf(t1 - rg.y);
      const float d2 = fabsf(t2 - rg.z);
      const float d3 = fabsf(t3 - rg.w);
      const float k = 1.0f / 9.0f;
      float rl = 0.0f;
      rl += (d0 < k) ? 4.5f * d0 * d0 : d0 - 0.5f * k;
      rl += (d1 < k) ? 4.5f * d1 * d1 : d1 - 0.5f * k;
      rl += (d2 < k) ? 4.5f * d2 * d2 : d2 - 0.5f * k;
      rl += (d3 < k) ? 4.5f * d3 * d3 : d3 - 0.5f * k;
      reg_local = rl;
    }
  }
  s_state[tid] = (unsigned char)state;
  s_cidx[tid] = (unsigned char)cidx;
  __syncthreads();

  // coalesced focal-loss pass over this block's classification rows (float4)
  const int n_anch = min(APB, A_ - a0);
  const float4* base = (const float4*)(cls + ((size_t)b * A_ + a0) * C_);
  const int total4 = n_anch * (C_ / 4);
  for (int i4 = tid; i4 < total4; i4 += APB) {
    const int al = i4 / 20;          // 20 float4 per row of 80
    const int st = s_state[al];
    if (st == 0) continue;           // ignore row: contributes 0, skip the load
    const float4 v = base[i4];
    const int c0 = (i4 - al * 20) * 4;
    const int ci = (st == 2) ? (int)s_cidx[al] : -1;
    const float pv[4] = {v.x, v.y, v.z, v.w};
#pragma unroll
    for (int j = 0; j < 4; ++j) {
      const float p = fminf(fmaxf(pv[j], 1e-4f), 1.0f - 1e-4f);
      if (c0 + j == ci)
        cls_local += 0.25f * (1.0f - p) * (1.0f - p) * (-__logf(p));
      else
        cls_local += 0.75f * p * p * (-__logf(1.0f - p));
    }
  }

  // block reduce cls_local, reg_local, pos_local
  const int lane = tid & 63, wid = tid >> 6;
#pragma unroll
  for (int off = 32; off; off >>= 1) {
    cls_local += __shfl_down(cls_local, off);
    reg_local += __shfl_down(reg_local, off);
    pos_local += __shfl_down(pos_local, off);
  }
  if (lane == 0) {
    s_c[wid] = cls_local;
    s_r[wid] = reg_local;
    s_p[wid] = pos_local;
  }
  __syncthreads();
  if (tid == 0) {
    const float c = s_c[0] + s_c[1] + s_c[2] + s_c[3];
    const float r = s_r[0] + s_r[1] + s_r[2] + s_r[3];
    const int p = s_p[0] + s_p[1] + s_p[2] + s_p[3];
    atomicAdd(&ws->cls_sum[b], (double)c);
    atomicAdd(&ws->reg_sum[b], (double)r);
    if (p) atomicAdd(&ws->num_pos[b], (unsigned)p);
  }
}

__global__ void focal_final(const float* __restrict__ ann,
                            const Ws* __restrict__ ws,
                            float* __restrict__ out) {
  const int tid = threadIdx.x;
  float clf = 0.0f, rgl = 0.0f;
  if (tid < B_) {
    bool any_valid = false;
    for (int m = 0; m < M_; ++m) {
      if (ann[tid * M_ * 5 + m * 5 + 4] != -1.0f) { any_valid = true; break; }
    }
    const float np_ = (float)ws->num_pos[tid];
    const float denom = fmaxf(np_, 1.0f);
    clf = any_valid ? (float)(ws->cls_sum[tid]) / denom : 0.0f;
    rgl = (np_ > 0.0f) ? (float)(ws->reg_sum[tid]) / (4.0f * denom) : 0.0f;
  }
#pragma unroll
  for (int off = 32; off; off >>= 1) {
    clf += __shfl_down(clf, off);
    rgl += __shfl_down(rgl, off);
  }
  if (tid == 0) {
    out[0] = clf * (1.0f / (float)B_);
    out[1] = rgl * (1.0f / (float)B_);
  }
}

extern "C" void kernel_launch(void* const* d_in, const int* in_sizes, int n_in,
                              void* d_out, int out_size, void* d_ws, size_t ws_size,
                              hipStream_t stream) {
  const float* cls = (const float*)d_in[0];
  const float* reg = (const float*)d_in[1];
  const float* anchors = (const float*)d_in[2];
  const float* ann = (const float*)d_in[3];
  float* out = (float*)d_out;
  Ws* ws = (Ws*)d_ws;

  hipMemsetAsync(ws, 0, sizeof(Ws), stream);

  dim3 grid((A_ + APB - 1) / APB, B_);
  focal_main<<<grid, APB, 0, stream>>>(cls, reg, anchors, ann, ws);
  focal_final<<<1, 64, 0, stream>>>(ann, ws, out);
}